// Round 13
// baseline (105.051 us; speedup 1.0000x reference)
//
#include <hip/hip_runtime.h>

// ASTDecoder: batched GCN on fixed banded graph, 2048 graphs x 256 nodes.
// Only 9 distinct rows/graph survive 3 layers. History: 102 -> 92 -> 78 ->
// 73 -> 65.6 -> 66.4 -> 77.9 -> 74.1 -> 64.5 -> 74.5 -> probe(2A+B)=84.4.
// Probe decoded: A ~= 18us (per-wave weight re-reads: each wave streamed
// 80-144KB of weight columns through L1 for ONE graph), B ~= 48us (5.5TB/s).
// R13: 4 graphs/wave amortizes weight loads 4x; EVERY wave computes the
// cheap interior chain + O8 (~3us) and immediately streams 120 nodes x 4
// graphs (all 268MB queued by ~5us); boundary waves then compute the 8
// boundary rows + final UNDER the HBM drain. Zero barriers (wave-private
// LDS only). 256 blocks x 256 threads (4 waves, 1 block/CU).

#define NB   2048
#define EMB  256
#define HID  64
#define ODIM 128
#define NN   256
#define GPB  8            // graphs per block (2 quads x 4)
#define NBLK (NB / GPB)   // 256 blocks

typedef float f32x4 __attribute__((ext_vector_type(4)));

__device__ __forceinline__ float dinvf(int j) {
  // deg: node0=3, node1=4, nodes 2..253=5 (mirror symmetric); only j<=9 used.
  if (j == 0) return 0.57735026918962576f;  // 1/sqrt(3)
  if (j == 1) return 0.5f;                  // 1/sqrt(4)
  return 0.44721359549995794f;              // 1/sqrt(5)
}

// Banded mix for one graph: rows i<NDN from row-GEMV results accR (i<ND) and
// the interior chain pre-activation g8. Writes relu'd rows into LDS.
template <int ND>
__device__ __forceinline__ void mix_rows(const float* accR, float g8, float cb,
                                         float* xrow, int j) {
  constexpr int NDN = (ND + 2 < 4) ? 4 : (ND + 2);
  #pragma unroll
  for (int i = 0; i < NDN; ++i) {
    const float di = dinvf(i);
    float acc = 0.f;
    #pragma unroll
    for (int jj = (i >= 2 ? i - 2 : 0); jj <= i + 2; ++jj) {
      const float v = (jj < ND) ? accR[jj] : g8;
      acc = fmaf(di * dinvf(jj), v, acc);
    }
    xrow[i * HID + j] = fmaxf(acc + cb, 0.f);
  }
}

__global__ __launch_bounds__(256) void gcn_fused(
    const float* __restrict__ emb,
    const float* __restrict__ W_emb,
    const float* __restrict__ b_emb,
    const float* __restrict__ convW,
    const float* __restrict__ convB,
    const float* __restrict__ Wout,
    const float* __restrict__ bout,
    float* __restrict__ out)
{
  const int tid   = threadIdx.x;
  const int lane  = tid & 63;
  const int wid   = tid >> 6;        // 0..3
  const int wslot = wid & 1;         // graph quad 0 or 1
  const int gq    = blockIdx.x * GPB + wslot * 4;   // first of this wave's 4 graphs
  const int j     = lane;

  __shared__ __align__(16) float e_p[4][4][EMB];     // 16 KB per-wave staged emb
  __shared__ __align__(16) float Xc[4][4][4][HID];   // 16 KB chain levels 0..3
  __shared__ __align__(16) float Xr[2][4][8][HID];   // 8 KB boundary rows
  __shared__ __align__(16) float Ob[4][4][ODIM];     // 8 KB O8 bounce

  // per-wave private e staging — NO barrier anywhere in this kernel
  #pragma unroll
  for (int g = 0; g < 4; ++g)
    *reinterpret_cast<f32x4*>(&e_p[wid][g][lane * 4]) =
        *reinterpret_cast<const f32x4*>(&emb[(size_t)(gq + g) * EMB + lane * 4]);

  // ---- init: x8[g] = e[g] @ W_emb + b_emb (weights shared across 4 graphs)
  float x8[4];
  {
    float acc[4] = {0.f, 0.f, 0.f, 0.f};
    #pragma unroll 8
    for (int k0 = 0; k0 < EMB; k0 += 4) {
      float w[4];
      #pragma unroll
      for (int c = 0; c < 4; ++c) w[c] = W_emb[(k0 + c) * HID + j];
      #pragma unroll
      for (int g = 0; g < 4; ++g) {
        const f32x4 ev = *reinterpret_cast<const f32x4*>(&e_p[wid][g][k0]);
        acc[g] = fmaf(ev[0], w[0], acc[g]);
        acc[g] = fmaf(ev[1], w[1], acc[g]);
        acc[g] = fmaf(ev[2], w[2], acc[g]);
        acc[g] = fmaf(ev[3], w[3], acc[g]);
      }
    }
    const float be = b_emb[j];
    #pragma unroll
    for (int g = 0; g < 4; ++g) x8[g] = acc[g] + be;
  }

  // ---- interior chain, levels 0..3; keep pre-activation g8 per layer (regs)
  float g8r[3][4];
  #pragma unroll
  for (int l = 0; l < 3; ++l) {
    #pragma unroll
    for (int g = 0; g < 4; ++g) Xc[wid][g][l][j] = x8[g];
    const float* W = convW + l * HID * HID;
    float acc[4] = {0.f, 0.f, 0.f, 0.f};
    #pragma unroll 4
    for (int k0 = 0; k0 < HID; k0 += 4) {
      float w[4];
      #pragma unroll
      for (int c = 0; c < 4; ++c) w[c] = W[(k0 + c) * HID + j];
      #pragma unroll
      for (int g = 0; g < 4; ++g) {
        const f32x4 xv = *reinterpret_cast<const f32x4*>(&Xc[wid][g][l][k0]);
        acc[g] = fmaf(xv[0], w[0], acc[g]);
        acc[g] = fmaf(xv[1], w[1], acc[g]);
        acc[g] = fmaf(xv[2], w[2], acc[g]);
        acc[g] = fmaf(xv[3], w[3], acc[g]);
      }
    }
    const float cb = convB[l * HID + j];
    #pragma unroll
    for (int g = 0; g < 4; ++g) {
      g8r[l][g] = acc[g];
      x8[g] = fmaxf(acc[g] + cb, 0.f);
    }
  }
  #pragma unroll
  for (int g = 0; g < 4; ++g) Xc[wid][g][3][j] = x8[g];

  // ---- O8 = chain level 3 @ Wout + bout -> Ob (f32x4 bounce)
  {
    float a0[4], a1[4];
    const float bo0 = bout[j], bo1 = bout[j + 64];
    #pragma unroll
    for (int g = 0; g < 4; ++g) { a0[g] = bo0; a1[g] = bo1; }
    #pragma unroll 4
    for (int k0 = 0; k0 < HID; k0 += 4) {
      float w0[4], w1[4];
      #pragma unroll
      for (int c = 0; c < 4; ++c) {
        w0[c] = Wout[(k0 + c) * ODIM + j];
        w1[c] = Wout[(k0 + c) * ODIM + 64 + j];
      }
      #pragma unroll
      for (int g = 0; g < 4; ++g) {
        const f32x4 xv = *reinterpret_cast<const f32x4*>(&Xc[wid][g][3][k0]);
        #pragma unroll
        for (int c = 0; c < 4; ++c) {
          a0[g] = fmaf(xv[c], w0[c], a0[g]);
          a1[g] = fmaf(xv[c], w1[c], a1[g]);
        }
      }
    }
    #pragma unroll
    for (int g = 0; g < 4; ++g) {
      Ob[wid][g][j]      = a0[g];
      Ob[wid][g][j + 64] = a1[g];
    }
  }

  // ---- stream interior nodes NOW (94% of bytes queued ~4us in).
  // interior waves: nodes 8..127; boundary waves: nodes 128..247.
  {
    const int q = lane & 31, half = lane >> 5;
    const int nbase = (wid < 2) ? 8 : 128;
    #pragma unroll
    for (int g = 0; g < 4; ++g) {
      f32x4* og4 = reinterpret_cast<f32x4*>(out + (size_t)(gq + g) * NN * ODIM);
      const f32x4 vint = *reinterpret_cast<const f32x4*>(&Ob[wid][g][q * 4]);
      #pragma unroll 6
      for (int it = 0; it < 60; ++it) {
        const int node = nbase + it * 2 + half;
        __builtin_nontemporal_store(vint, &og4[node * 32 + q]);
      }
    }
  }

  if (wid >= 2) {
    // ================= boundary rows — hidden under the HBM drain =================
    const int bw = wid - 2;
    // L0: mix from g8 only (ND=0)
    {
      const float cb = convB[j];
      #pragma unroll
      for (int g = 0; g < 4; ++g)
        mix_rows<0>(&g8r[0][g], g8r[0][g], cb, &Xr[bw][g][0][0], j);
    }
    // L1: 4 row-GEMVs per graph (ND=4)
    {
      const float* W = convW + 1 * HID * HID;
      float aR[4][4] = {};
      #pragma unroll 4
      for (int k0 = 0; k0 < HID; k0 += 4) {
        float w[4];
        #pragma unroll
        for (int c = 0; c < 4; ++c) w[c] = W[(k0 + c) * HID + j];
        #pragma unroll
        for (int g = 0; g < 4; ++g) {
          #pragma unroll
          for (int r = 0; r < 4; ++r) {
            const f32x4 xv = *reinterpret_cast<const f32x4*>(&Xr[bw][g][r][k0]);
            aR[g][r] = fmaf(xv[0], w[0], aR[g][r]);
            aR[g][r] = fmaf(xv[1], w[1], aR[g][r]);
            aR[g][r] = fmaf(xv[2], w[2], aR[g][r]);
            aR[g][r] = fmaf(xv[3], w[3], aR[g][r]);
          }
        }
      }
      const float cb = convB[HID + j];
      #pragma unroll
      for (int g = 0; g < 4; ++g)
        mix_rows<4>(aR[g], g8r[1][g], cb, &Xr[bw][g][0][0], j);
    }
    // L2: 6 row-GEMVs per graph (ND=6)
    {
      const float* W = convW + 2 * HID * HID;
      float aR[4][6] = {};
      #pragma unroll 4
      for (int k0 = 0; k0 < HID; k0 += 4) {
        float w[4];
        #pragma unroll
        for (int c = 0; c < 4; ++c) w[c] = W[(k0 + c) * HID + j];
        #pragma unroll
        for (int g = 0; g < 4; ++g) {
          #pragma unroll
          for (int r = 0; r < 6; ++r) {
            const f32x4 xv = *reinterpret_cast<const f32x4*>(&Xr[bw][g][r][k0]);
            aR[g][r] = fmaf(xv[0], w[0], aR[g][r]);
            aR[g][r] = fmaf(xv[1], w[1], aR[g][r]);
            aR[g][r] = fmaf(xv[2], w[2], aR[g][r]);
            aR[g][r] = fmaf(xv[3], w[3], aR[g][r]);
          }
        }
      }
      const float cb = convB[2 * HID + j];
      #pragma unroll
      for (int g = 0; g < 4; ++g)
        mix_rows<6>(aR[g], g8r[2][g], cb, &Xr[bw][g][0][0], j);
    }
    // final: 8 rows x 2 col-halves; write nodes 0..7 and mirrored 248..255
    #pragma unroll
    for (int c = 0; c < 2; ++c) {
      float aB[4][8];
      const float bo = bout[c * 64 + j];
      #pragma unroll
      for (int g = 0; g < 4; ++g)
        #pragma unroll
        for (int r = 0; r < 8; ++r) aB[g][r] = bo;
      #pragma unroll 4
      for (int k0 = 0; k0 < HID; k0 += 4) {
        float w[4];
        #pragma unroll
        for (int cc = 0; cc < 4; ++cc) w[cc] = Wout[(k0 + cc) * ODIM + c * 64 + j];
        #pragma unroll
        for (int g = 0; g < 4; ++g) {
          #pragma unroll
          for (int r = 0; r < 8; ++r) {
            const f32x4 xv = *reinterpret_cast<const f32x4*>(&Xr[bw][g][r][k0]);
            aB[g][r] = fmaf(xv[0], w[0], aB[g][r]);
            aB[g][r] = fmaf(xv[1], w[1], aB[g][r]);
            aB[g][r] = fmaf(xv[2], w[2], aB[g][r]);
            aB[g][r] = fmaf(xv[3], w[3], aB[g][r]);
          }
        }
      }
      #pragma unroll
      for (int g = 0; g < 4; ++g) {
        float* og = out + (size_t)(gq + g) * NN * ODIM;
        #pragma unroll
        for (int n = 0; n < 8; ++n) {
          __builtin_nontemporal_store(aB[g][n], &og[n * ODIM + c * 64 + j]);
          __builtin_nontemporal_store(aB[g][n], &og[(255 - n) * ODIM + c * 64 + j]);
        }
      }
    }
  }
}

extern "C" void kernel_launch(void* const* d_in, const int* in_sizes, int n_in,
                              void* d_out, int out_size, void* d_ws, size_t ws_size,
                              hipStream_t stream) {
  const float* emb   = (const float*)d_in[0];
  const float* W_emb = (const float*)d_in[1];
  const float* b_emb = (const float*)d_in[2];
  const float* convW = (const float*)d_in[3];
  const float* convB = (const float*)d_in[4];
  const float* Wout  = (const float*)d_in[5];
  const float* bout  = (const float*)d_in[6];
  float* out = (float*)d_out;

  hipLaunchKernelGGL(gcn_fused, dim3(NBLK), dim3(256), 0, stream,
                     emb, W_emb, b_emb, convW, convB, Wout, bout, out);
}

// Round 14
// 76.366 us; speedup vs baseline: 1.3756x; 1.3756x over previous
//
#include <hip/hip_runtime.h>

// ASTDecoder: batched GCN, 2048 graphs x 256 nodes; 9 distinct rows/graph.
// History: 102->92->78->73->65.6->66.4->77.9->74.1->64.5->74.5->84.4(probe)
// ->105(R13). Probe: compute A ~= 18us, drain ~= 48us@32w / 44us@16w.
// A's 18us = per-CU port serialization: 16 waves/CU x ~88KB weight reads
// through ONE L1/LDS port. R11's readlane fix was right but launch_bounds
// (512,4) forced 128-VGPR spills. R14: readlane chain (VALU pipe, 4 SIMDs
// parallel, no memory port) with chunked weight loads and no big arrays;
// 4 compute waves (2 graphs each) -> barrier -> 12 waves stream interior
// (proven drain shape) while compute waves do boundary under the drain.

#define NB   2048
#define EMB  256
#define HID  64
#define ODIM 128
#define NN   256
#define GPB  8            // graphs per block
#define NBLK (NB / GPB)   // 256 blocks x 1024 threads = 1 block/CU, 16 waves

typedef float f32x4 __attribute__((ext_vector_type(4)));

__device__ __forceinline__ float rl(float v, int k) {
  // broadcast lane k (VALU op; result is a scalar operand for the FMA)
  return __uint_as_float(__builtin_amdgcn_readlane(__float_as_uint(v), k));
}

__device__ __forceinline__ float dinvf(int j) {
  // deg: node0=3, node1=4, nodes 2..253=5 (mirror symmetric); only j<=9 used.
  if (j == 0) return 0.57735026918962576f;  // 1/sqrt(3)
  if (j == 1) return 0.5f;                  // 1/sqrt(4)
  return 0.44721359549995794f;              // 1/sqrt(5)
}

__global__ __launch_bounds__(1024) void gcn_fused(
    const float* __restrict__ emb,
    const float* __restrict__ W_emb,
    const float* __restrict__ b_emb,
    const float* __restrict__ convW,
    const float* __restrict__ convB,
    const float* __restrict__ Wout,
    const float* __restrict__ bout,
    float* __restrict__ out)
{
  const int tid   = threadIdx.x;
  const int lane  = tid & 63;
  const int wid   = tid >> 6;        // 0..15
  const int j     = lane;
  const int gbase = blockIdx.x * GPB;

  __shared__ __align__(16) float Ob[GPB][ODIM];   // 4 KB: interior O rows

  float g8r[3][2];   // per-layer interior pre-activations (compute waves)

  if (wid < 4) {
    // ======== compute waves: graphs gA=2*wid, gB=2*wid+1 ========
    const int gA = gbase + wid * 2, gB = gA + 1;

    // e in registers: lane j holds e[c*64+j], c=0..3
    float eA[4], eB[4];
    #pragma unroll
    for (int c = 0; c < 4; ++c) {
      eA[c] = emb[(size_t)gA * EMB + c * 64 + j];
      eB[c] = emb[(size_t)gB * EMB + c * 64 + j];
    }

    // init: x8 = e @ W_emb + b_emb  (w: coalesced dword; x: readlane)
    float x8a = 0.f, x8b = 0.f;
    #pragma unroll
    for (int c = 0; c < 4; ++c) {
      #pragma unroll 8
      for (int kk = 0; kk < 64; ++kk) {
        const float w = W_emb[(c * 64 + kk) * HID + j];
        x8a = fmaf(rl(eA[c], kk), w, x8a);
        x8b = fmaf(rl(eB[c], kk), w, x8b);
      }
    }
    const float be = b_emb[j];
    x8a += be; x8b += be;

    // 3-layer interior chain; save pre-activations for the boundary path
    #pragma unroll
    for (int l = 0; l < 3; ++l) {
      const float* W = convW + l * HID * HID;
      float a0 = 0.f, a1 = 0.f;
      #pragma unroll 8
      for (int kk = 0; kk < 64; ++kk) {
        const float w = W[kk * HID + j];
        a0 = fmaf(rl(x8a, kk), w, a0);
        a1 = fmaf(rl(x8b, kk), w, a1);
      }
      const float cb = convB[l * HID + j];
      g8r[l][0] = a0; g8r[l][1] = a1;
      x8a = fmaxf(a0 + cb, 0.f);
      x8b = fmaxf(a1 + cb, 0.f);
    }

    // O8 = x8 @ Wout + bout -> LDS (both column halves)
    #pragma unroll
    for (int c = 0; c < 2; ++c) {
      float o0 = bout[c * 64 + j], o1 = o0;
      #pragma unroll 8
      for (int kk = 0; kk < 64; ++kk) {
        const float w = Wout[kk * ODIM + c * 64 + j];
        o0 = fmaf(rl(x8a, kk), w, o0);
        o1 = fmaf(rl(x8b, kk), w, o1);
      }
      Ob[wid * 2 + 0][c * 64 + j] = o0;
      Ob[wid * 2 + 1][c * 64 + j] = o1;
    }
  }
  __syncthreads();   // the only barrier

  if (wid >= 4) {
    // ======== 12 streaming waves: 8 graphs x 120 node-pairs = 960 pairs ====
    const int q = lane & 31, half = lane >> 5;
    int pairIdx = (wid - 4) * 80;
    #pragma unroll 4
    for (int it = 0; it < 80; ++it, ++pairIdx) {
      const unsigned g = ((unsigned)pairIdx * 1118482u) >> 27;   // /120
      const int node = 8 + (pairIdx - (int)g * 120) * 2 + half;  // 8..247
      const f32x4 v = *reinterpret_cast<const f32x4*>(&Ob[g][q * 4]);
      f32x4* og4 = reinterpret_cast<f32x4*>(out + (size_t)(gbase + g) * NN * ODIM);
      __builtin_nontemporal_store(v, &og4[node * 32 + q]);
    }
  } else {
    // ======== boundary rows for gA,gB — hidden under the HBM drain ========
    const int gA = gbase + wid * 2, gB = gA + 1;
    float xbA[8], xbB[8];

    // L0 (ND=0, NDN=4): all band values are the interior pre-activation
    {
      const float cb = convB[j];
      #pragma unroll
      for (int i = 0; i < 4; ++i) {
        float s = 0.f;
        #pragma unroll
        for (int jj = (i >= 2 ? i - 2 : 0); jj <= i + 2; ++jj)
          s += dinvf(jj);
        const float di = dinvf(i);
        xbA[i] = fmaxf(fmaf(di * s, g8r[0][0], cb), 0.f);
        xbB[i] = fmaxf(fmaf(di * s, g8r[0][1], cb), 0.f);
      }
    }
    // L1 (ND=4 -> NDN=6)
    {
      const float* W = convW + 1 * HID * HID;
      float aA[4] = {}, aB[4] = {};
      #pragma unroll 8
      for (int kk = 0; kk < 64; ++kk) {
        const float w = W[kk * HID + j];
        #pragma unroll
        for (int r = 0; r < 4; ++r) {
          aA[r] = fmaf(rl(xbA[r], kk), w, aA[r]);
          aB[r] = fmaf(rl(xbB[r], kk), w, aB[r]);
        }
      }
      const float cb = convB[HID + j];
      float nA[6], nB[6];
      #pragma unroll
      for (int i = 0; i < 6; ++i) {
        const float di = dinvf(i);
        float sA = 0.f, sB = 0.f;
        #pragma unroll
        for (int jj = (i >= 2 ? i - 2 : 0); jj <= i + 2; ++jj) {
          const float c2 = di * dinvf(jj);
          sA = fmaf(c2, (jj < 4) ? aA[jj] : g8r[1][0], sA);
          sB = fmaf(c2, (jj < 4) ? aB[jj] : g8r[1][1], sB);
        }
        nA[i] = fmaxf(sA + cb, 0.f);
        nB[i] = fmaxf(sB + cb, 0.f);
      }
      #pragma unroll
      for (int i = 0; i < 6; ++i) { xbA[i] = nA[i]; xbB[i] = nB[i]; }
    }
    // L2 (ND=6 -> NDN=8)
    {
      const float* W = convW + 2 * HID * HID;
      float aA[6] = {}, aB[6] = {};
      #pragma unroll 4
      for (int kk = 0; kk < 64; ++kk) {
        const float w = W[kk * HID + j];
        #pragma unroll
        for (int r = 0; r < 6; ++r) {
          aA[r] = fmaf(rl(xbA[r], kk), w, aA[r]);
          aB[r] = fmaf(rl(xbB[r], kk), w, aB[r]);
        }
      }
      const float cb = convB[2 * HID + j];
      float nA[8], nB[8];
      #pragma unroll
      for (int i = 0; i < 8; ++i) {
        const float di = dinvf(i);
        float sA = 0.f, sB = 0.f;
        #pragma unroll
        for (int jj = (i >= 2 ? i - 2 : 0); jj <= i + 2; ++jj) {
          const float c2 = di * dinvf(jj);
          sA = fmaf(c2, (jj < 6) ? aA[jj] : g8r[2][0], sA);
          sB = fmaf(c2, (jj < 6) ? aB[jj] : g8r[2][1], sB);
        }
        nA[i] = fmaxf(sA + cb, 0.f);
        nB[i] = fmaxf(sB + cb, 0.f);
      }
      #pragma unroll
      for (int i = 0; i < 8; ++i) { xbA[i] = nA[i]; xbB[i] = nB[i]; }
    }
    // final: O rows 0..7 for both graphs; write nodes 0..7 + mirrors
    float* ogA = out + (size_t)gA * NN * ODIM;
    float* ogB = out + (size_t)gB * NN * ODIM;
    #pragma unroll
    for (int c = 0; c < 2; ++c) {
      const float bo = bout[c * 64 + j];
      float fA[8], fB[8];
      #pragma unroll
      for (int r = 0; r < 8; ++r) { fA[r] = bo; fB[r] = bo; }
      #pragma unroll 4
      for (int kk = 0; kk < 64; ++kk) {
        const float w = Wout[kk * ODIM + c * 64 + j];
        #pragma unroll
        for (int r = 0; r < 8; ++r) {
          fA[r] = fmaf(rl(xbA[r], kk), w, fA[r]);
          fB[r] = fmaf(rl(xbB[r], kk), w, fB[r]);
        }
      }
      #pragma unroll
      for (int n = 0; n < 8; ++n) {
        __builtin_nontemporal_store(fA[n], &ogA[n * ODIM + c * 64 + j]);
        __builtin_nontemporal_store(fA[n], &ogA[(255 - n) * ODIM + c * 64 + j]);
        __builtin_nontemporal_store(fB[n], &ogB[n * ODIM + c * 64 + j]);
        __builtin_nontemporal_store(fB[n], &ogB[(255 - n) * ODIM + c * 64 + j]);
      }
    }
  }
}

extern "C" void kernel_launch(void* const* d_in, const int* in_sizes, int n_in,
                              void* d_out, int out_size, void* d_ws, size_t ws_size,
                              hipStream_t stream) {
  const float* emb   = (const float*)d_in[0];
  const float* W_emb = (const float*)d_in[1];
  const float* b_emb = (const float*)d_in[2];
  const float* convW = (const float*)d_in[3];
  const float* convB = (const float*)d_in[4];
  const float* Wout  = (const float*)d_in[5];
  const float* bout  = (const float*)d_in[6];
  float* out = (float*)d_out;

  hipLaunchKernelGGL(gcn_fused, dim3(NBLK), dim3(1024), 0, stream,
                     emb, W_emb, b_emb, convW, convB, Wout, bout, out);
}

// Round 15
// 51.696 us; speedup vs baseline: 2.0321x; 1.4772x over previous
//
#include <hip/hip_runtime.h>

// ASTDecoder: batched GCN on fixed banded graph, 2048 graphs x 256 nodes.
// Only 9 distinct rows/graph survive 3 layers. History: 102 -> 92 -> 78 ->
// 73 -> 65.6 -> 66.4 -> 77.9 -> 74.1 -> 64.5(R10) -> 74.5 -> 84.4(probe) ->
// 105 -> 76.4. Probe fixed warm-A=18us. Empirical store table: every NT
// streamer ~4.5-5.2 TB/s (R6/R10 fused, R2); every PLAIN streamer faster
// (fill 6.9, R7-B 5.5). R15 = R10 byte-identical except ALL nontemporal
// stores -> plain stores (single-variable test of the NT hypothesis).

#define NB   2048
#define EMB  256
#define HID  64
#define ODIM 128
#define NN   256
#define MG   8            // graphs per block
#define NBLK (NB / MG)    // 256 blocks = 1/CU

typedef float f32x4 __attribute__((ext_vector_type(4)));

__device__ __forceinline__ float dinvf(int j) {
  // deg: node0=3, node1=4, nodes 2..253=5 (mirror symmetric); only j<=9 used.
  if (j == 0) return 0.57735026918962576f;  // 1/sqrt(3)
  if (j == 1) return 0.5f;                  // 1/sqrt(4)
  return 0.44721359549995794f;              // 1/sqrt(5)
}

struct Smem {
  float wbuf[20480];        // 80KB: phase01 = W_emb (16384); later convW(12288)+Wout(8192)
  float e[MG][EMB];         // 8KB
  float red[8][MG][HID];    // 16KB
  float X8s[MG][4][HID];    // 8KB  interior chain levels
  float X8b[MG][4][HID];    // 8KB  boundary waves' chain copy
  float Xb[MG][8][HID];     // 16KB boundary rows
  float O8[MG][ODIM];       // 4KB  interior output row (store bounce)
  float cb[3][HID];         // convB
  float be[HID];            // b_emb
  float bo[ODIM];           // bout
};                          // ~141.5KB -> 1 block/CU

// One boundary-path GCN layer; all weight reads from LDS, all dataflow
// intra-wave (lockstep, no barriers).
template <int L, int ND_IN>
__device__ __forceinline__ void boundary_layer(Smem& s, int g, int j) {
  const float* W = s.wbuf + L * HID * HID;   // LDS convW

  // interior-row chain step (pre-bias value needed for the mix)
  float g8 = 0.f;
  #pragma unroll
  for (int k0 = 0; k0 < HID; k0 += 4) {
    const f32x4 xv = *reinterpret_cast<const f32x4*>(&s.X8b[g][L][k0]);
    g8 = fmaf(xv[0], W[(k0 + 0) * HID + j], g8);
    g8 = fmaf(xv[1], W[(k0 + 1) * HID + j], g8);
    g8 = fmaf(xv[2], W[(k0 + 2) * HID + j], g8);
    g8 = fmaf(xv[3], W[(k0 + 3) * HID + j], g8);
  }
  s.X8b[g][L + 1][j] = fmaxf(g8 + s.cb[L][j], 0.f);

  // boundary G rows (register accumulators; Xb broadcast-read from LDS)
  float accR[ND_IN > 0 ? ND_IN : 1];
  #pragma unroll
  for (int r = 0; r < (ND_IN > 0 ? ND_IN : 1); ++r) accR[r] = 0.f;
  if constexpr (ND_IN > 0) {
    #pragma unroll
    for (int k0 = 0; k0 < HID; k0 += 4) {
      float w[4];
      #pragma unroll
      for (int c = 0; c < 4; ++c) w[c] = W[(k0 + c) * HID + j];
      #pragma unroll
      for (int r = 0; r < ND_IN; ++r) {
        const f32x4 xv = *reinterpret_cast<const f32x4*>(&s.Xb[g][r][k0]);
        accR[r] = fmaf(xv[0], w[0], accR[r]);
        accR[r] = fmaf(xv[1], w[1], accR[r]);
        accR[r] = fmaf(xv[2], w[2], accR[r]);
        accR[r] = fmaf(xv[3], w[3], accR[r]);
      }
    }
  }

  // banded mix
  constexpr int NDN = (ND_IN + 2 < 4) ? 4 : (ND_IN + 2);
  float xnew[NDN];
  #pragma unroll
  for (int i = 0; i < NDN; ++i) {
    const float di = dinvf(i);
    float acc = 0.f;
    #pragma unroll
    for (int jj = (i >= 2 ? i - 2 : 0); jj <= i + 2; ++jj) {
      const float v = (jj < ND_IN) ? accR[jj] : g8;
      acc = fmaf(di * dinvf(jj), v, acc);
    }
    xnew[i] = fmaxf(acc + s.cb[L][j], 0.f);
  }
  #pragma unroll
  for (int i = 0; i < NDN; ++i) s.Xb[g][i][j] = xnew[i];
}

__global__ __launch_bounds__(1024) void gcn_fused(
    const float* __restrict__ emb,
    const float* __restrict__ W_emb,
    const float* __restrict__ b_emb,
    const float* __restrict__ convW,
    const float* __restrict__ convB,
    const float* __restrict__ Wout,
    const float* __restrict__ bout,
    float* __restrict__ out)
{
  const int tid   = threadIdx.x;
  const int lane  = tid & 63;
  const int wid   = tid >> 6;          // 0..15
  const int gbase = blockIdx.x * MG;

  __shared__ __align__(16) Smem s;

  // ---- phase 0: stage W_emb (64KB), embeddings (8KB), biases ----
  {
    const f32x4* W4  = reinterpret_cast<const f32x4*>(W_emb);
    f32x4*       wb4 = reinterpret_cast<f32x4*>(s.wbuf);
    #pragma unroll
    for (int i = 0; i < 4; ++i) wb4[tid + i * 1024] = W4[tid + i * 1024];
    if (tid < 512) {
      const int g = tid >> 6, q = tid & 63;
      *reinterpret_cast<f32x4*>(&s.e[g][q * 4]) =
          *reinterpret_cast<const f32x4*>(&emb[(size_t)(gbase + g) * EMB + q * 4]);
    }
    if (tid < HID)                        s.be[tid] = b_emb[tid];
    else if (tid >= 64  && tid < 256)     { const int t = tid - 64; s.cb[t >> 6][t & 63] = convB[t]; }
    else if (tid >= 256 && tid < 384)     s.bo[tid - 256] = bout[tid - 256];
  }
  __syncthreads();

  // ---- phase 1: init split-K (waves 0..7, 32 k's each, all 8 graphs) ----
  if (wid < 8) {
    const int k0 = wid * 32, j = lane;
    float a[MG] = {};
    for (int kk = 0; kk < 32; ++kk) {
      const float w = s.wbuf[(k0 + kk) * HID + j];
      #pragma unroll
      for (int g = 0; g < MG; ++g) a[g] = fmaf(s.e[g][k0 + kk], w, a[g]);
    }
    #pragma unroll
    for (int g = 0; g < MG; ++g) s.red[wid][g][j] = a[g];
  }
  __syncthreads();

  // ---- phase 2: reduce into chain bases; stage convW+Wout over W_emb ----
  {
    const int g = wid & 7, j = lane;
    float v = s.be[j];
    #pragma unroll
    for (int q = 0; q < 8; ++q) v += s.red[q][g][j];
    if (wid < 8) s.X8s[g][0][j] = v;
    else         s.X8b[g][0][j] = v;
  }
  {
    const f32x4* cW4 = reinterpret_cast<const f32x4*>(convW);  // 3072 vec4
    const f32x4* Wo4 = reinterpret_cast<const f32x4*>(Wout);   // 2048 vec4
    f32x4*       wb4 = reinterpret_cast<f32x4*>(s.wbuf);
    #pragma unroll
    for (int i = 0; i < 5; ++i) {
      const int idx = tid + i * 1024;   // < 5120
      wb4[idx] = (idx < 3072) ? cW4[idx] : Wo4[idx - 3072];
    }
  }
  __syncthreads();   // last barrier — everything below is intra-wave

  const float* wo = s.wbuf + 12288;     // Wout in LDS [k*128 + col]
  const int g = wid & 7, j = lane;
  float* og = out + (size_t)(gbase + g) * NN * ODIM;

  if (wid < 8) {
    // ========== interior path (wave g): chain + O8 + 240-node stream ==========
    #pragma unroll
    for (int l = 0; l < 3; ++l) {
      const float* W = s.wbuf + l * HID * HID;
      float acc = 0.f;
      #pragma unroll
      for (int k0 = 0; k0 < HID; k0 += 4) {
        const f32x4 xv = *reinterpret_cast<const f32x4*>(&s.X8s[g][l][k0]);
        acc = fmaf(xv[0], W[(k0 + 0) * HID + j], acc);
        acc = fmaf(xv[1], W[(k0 + 1) * HID + j], acc);
        acc = fmaf(xv[2], W[(k0 + 2) * HID + j], acc);
        acc = fmaf(xv[3], W[(k0 + 3) * HID + j], acc);
      }
      s.X8s[g][l + 1][j] = fmaxf(acc + s.cb[l][j], 0.f);
    }
    float a0 = s.bo[j], a1 = s.bo[j + 64];
    #pragma unroll
    for (int k0 = 0; k0 < HID; k0 += 4) {
      const f32x4 xv = *reinterpret_cast<const f32x4*>(&s.X8s[g][3][k0]);
      #pragma unroll
      for (int c = 0; c < 4; ++c) {
        a0 = fmaf(xv[c], wo[(k0 + c) * ODIM + j], a0);
        a1 = fmaf(xv[c], wo[(k0 + c) * ODIM + j + 64], a1);
      }
    }
    s.O8[g][j]      = a0;
    s.O8[g][j + 64] = a1;

    // stream interior nodes 8..247 — PLAIN stores (the fill kernel's path)
    const int q = lane & 31, half = lane >> 5;
    const f32x4 vint = *reinterpret_cast<const f32x4*>(&s.O8[g][q * 4]);
    f32x4* og4 = reinterpret_cast<f32x4*>(og);
    #pragma unroll 8
    for (int it = 0; it < 120; ++it) {
      const int node = 8 + it * 2 + half;
      og4[node * 32 + q] = vint;
    }
  } else {
    // ========== boundary path (wave g+8): 8 rows + final + 16 nodes ==========
    boundary_layer<0, 0>(s, g, j);
    boundary_layer<1, 4>(s, g, j);
    boundary_layer<2, 6>(s, g, j);

    float aa[8], ab[8];
    #pragma unroll
    for (int r = 0; r < 8; ++r) { aa[r] = s.bo[j]; ab[r] = s.bo[j + 64]; }
    #pragma unroll
    for (int k0 = 0; k0 < HID; k0 += 4) {
      float w0[4], w1[4];
      #pragma unroll
      for (int c = 0; c < 4; ++c) {
        w0[c] = wo[(k0 + c) * ODIM + j];
        w1[c] = wo[(k0 + c) * ODIM + j + 64];
      }
      #pragma unroll
      for (int r = 0; r < 8; ++r) {
        const f32x4 xv = *reinterpret_cast<const f32x4*>(&s.Xb[g][r][k0]);
        #pragma unroll
        for (int c = 0; c < 4; ++c) {
          aa[r] = fmaf(xv[c], w0[c], aa[r]);
          ab[r] = fmaf(xv[c], w1[c], ab[r]);
        }
      }
    }

    // nodes 0..7 and mirrored 248..255; 256B-coalesced PLAIN dword stores
    #pragma unroll
    for (int n = 0; n < 8; ++n) {
      og[n * ODIM + j]              = aa[n];
      og[n * ODIM + 64 + j]         = ab[n];
      og[(255 - n) * ODIM + j]      = aa[n];
      og[(255 - n) * ODIM + 64 + j] = ab[n];
    }
  }
}

extern "C" void kernel_launch(void* const* d_in, const int* in_sizes, int n_in,
                              void* d_out, int out_size, void* d_ws, size_t ws_size,
                              hipStream_t stream) {
  const float* emb   = (const float*)d_in[0];
  const float* W_emb = (const float*)d_in[1];
  const float* b_emb = (const float*)d_in[2];
  const float* convW = (const float*)d_in[3];
  const float* convB = (const float*)d_in[4];
  const float* Wout  = (const float*)d_in[5];
  const float* bout  = (const float*)d_in[6];
  float* out = (float*)d_out;

  hipLaunchKernelGGL(gcn_fused, dim3(NBLK), dim3(1024), 0, stream,
                     emb, W_emb, b_emb, convW, convB, Wout, bout, out);
}